// Round 5
// baseline (3286.224 us; speedup 1.0000x reference)
//
#include <hip/hip_runtime.h>

#define EPS 1e-5f

// ---------------------------------------------------------------------------
// scatter_gemm_wreg2: level 1 (CIN=32, COUT=32). COUT lanes per row (lane=o),
// one coalesced 128-B atomic per row, W[k][:,o] in registers (k=blockIdx.y).
// 2-row software pipeline per iteration + 4 accumulators per row so two rows'
// idx+gather loads are in flight across each waitcnt stall (intra-wave MLP).
// Grids are exact (P % RPB == 0, RPB/GROUPS even) - no tail handling.
// ---------------------------------------------------------------------------
template <int CIN, int COUT, int RPB>
__global__ __launch_bounds__(256, 8) void scatter_gemm_wreg2(
    const float* __restrict__ x, const float* __restrict__ W,
    const int* __restrict__ in_idx, const int* __restrict__ out_idx,
    float* __restrict__ out, int P)
{
    const int GROUPS = 256 / COUT;          // 8
    const int ITERS = RPB / GROUPS;         // 8 (even)
    const int k = blockIdx.y;
    const int o = threadIdx.x % COUT;
    const int g = threadIdx.x / COUT;

    float wcol[CIN];
    const float* __restrict__ Wk = W + (size_t)k * CIN * COUT + o;
#pragma unroll
    for (int i = 0; i < CIN; ++i) wcol[i] = Wk[(size_t)i * COUT];

    const int rbase = k * P + blockIdx.x * RPB + g;

    for (int it = 0; it < ITERS; it += 2) {
        const int r0 = rbase + it * GROUPS;
        const int r1 = r0 + GROUPS;
        const int in0 = in_idx[r0];
        const int or0 = out_idx[r0];
        const int in1 = in_idx[r1];
        const int or1 = out_idx[r1];
        const float4* __restrict__ a4 = (const float4*)(x + (size_t)in0 * CIN);
        const float4* __restrict__ b4 = (const float4*)(x + (size_t)in1 * CIN);
        float aa0 = 0.f, aa1 = 0.f, aa2 = 0.f, aa3 = 0.f;
        float ba0 = 0.f, ba1 = 0.f, ba2 = 0.f, ba3 = 0.f;
#pragma unroll
        for (int i4 = 0; i4 < CIN / 4; ++i4) {
            const float4 av = a4[i4];
            const float4 bv = b4[i4];
            aa0 = fmaf(av.x, wcol[4 * i4 + 0], aa0);
            aa1 = fmaf(av.y, wcol[4 * i4 + 1], aa1);
            aa2 = fmaf(av.z, wcol[4 * i4 + 2], aa2);
            aa3 = fmaf(av.w, wcol[4 * i4 + 3], aa3);
            ba0 = fmaf(bv.x, wcol[4 * i4 + 0], ba0);
            ba1 = fmaf(bv.y, wcol[4 * i4 + 1], ba1);
            ba2 = fmaf(bv.z, wcol[4 * i4 + 2], ba2);
            ba3 = fmaf(bv.w, wcol[4 * i4 + 3], ba3);
        }
        atomicAdd(&out[(size_t)or0 * COUT + o], (aa0 + aa1) + (aa2 + aa3));
        atomicAdd(&out[(size_t)or1 * COUT + o], (ba0 + ba1) + (ba2 + ba3));
    }
}

// ---------------------------------------------------------------------------
// scatter_gemm_h2u: level 2 (CIN=64, COUT=32). 64 lanes per row: o=lane&31,
// h=lane>>5 selects CIN-half (wcol[32]). Partial dots combined via
// __shfl_xor(32); h==0 half issues the coalesced 128-B atomic.
// 2-row pipeline + 2 accumulators per row. Exact grids, even iteration count.
// ---------------------------------------------------------------------------
template <int CIN, int RPB>
__global__ __launch_bounds__(256, 8) void scatter_gemm_h2u(
    const float* __restrict__ x, const float* __restrict__ W,
    const int* __restrict__ in_idx, const int* __restrict__ out_idx,
    float* __restrict__ out, int P)
{
    const int COUT = 32;
    const int HC = CIN / 2;                 // 32
    const int WAVES = 4;
    const int ITERS = RPB / WAVES;          // 8 (even)
    const int k = blockIdx.y;
    const int lane = threadIdx.x & 63;
    const int w = threadIdx.x >> 6;
    const int o = lane & 31;
    const int h = lane >> 5;

    float wcol[HC];
    const float* __restrict__ Wk =
        W + (size_t)k * CIN * COUT + (size_t)h * HC * COUT + o;
#pragma unroll
    for (int i = 0; i < HC; ++i) wcol[i] = Wk[(size_t)i * COUT];

    const int rbase = k * P + blockIdx.x * RPB + w;

    for (int it = 0; it < ITERS; it += 2) {
        const int r0 = rbase + it * WAVES;
        const int r1 = r0 + WAVES;
        const int in0 = in_idx[r0];
        const int or0 = out_idx[r0];
        const int in1 = in_idx[r1];
        const int or1 = out_idx[r1];
        const float4* __restrict__ a4 =
            (const float4*)(x + (size_t)in0 * CIN + h * HC);
        const float4* __restrict__ b4 =
            (const float4*)(x + (size_t)in1 * CIN + h * HC);
        float aa0 = 0.f, aa1 = 0.f;
        float ba0 = 0.f, ba1 = 0.f;
#pragma unroll
        for (int i4 = 0; i4 < HC / 4; ++i4) {
            const float4 av = a4[i4];
            const float4 bv = b4[i4];
            aa0 = fmaf(av.x, wcol[4 * i4 + 0], aa0);
            aa1 = fmaf(av.y, wcol[4 * i4 + 1], aa1);
            aa0 = fmaf(av.z, wcol[4 * i4 + 2], aa0);
            aa1 = fmaf(av.w, wcol[4 * i4 + 3], aa1);
            ba0 = fmaf(bv.x, wcol[4 * i4 + 0], ba0);
            ba1 = fmaf(bv.y, wcol[4 * i4 + 1], ba1);
            ba0 = fmaf(bv.z, wcol[4 * i4 + 2], ba0);
            ba1 = fmaf(bv.w, wcol[4 * i4 + 3], ba1);
        }
        float acc0 = aa0 + aa1;
        float acc1 = ba0 + ba1;
        acc0 += __shfl_xor(acc0, 32);
        acc1 += __shfl_xor(acc1, 32);
        if (h == 0) {
            atomicAdd(&out[(size_t)or0 * COUT + o], acc0);
            atomicAdd(&out[(size_t)or1 * COUT + o], acc1);
        }
    }
}

// ---------------------------------------------------------------------------
// scatter_gemm_l3w: level 3 (CIN=128, COUT=64). Wave = (row-slot, CIN-half):
// w>>1 selects which of 2 concurrent rows, w&1 selects half -> wcol[64].
// Each half issues its own coalesced 256-B atomic (atomicAdd is commutative)
// -> no LDS combine, no __syncthreads, barrier-free pipelining.
// ---------------------------------------------------------------------------
template <int RPB>
__global__ __launch_bounds__(256, 4) void scatter_gemm_l3w(
    const float* __restrict__ x, const float* __restrict__ W,
    const int* __restrict__ in_idx, const int* __restrict__ out_idx,
    float* __restrict__ out, int P)
{
    const int CIN = 128, COUT = 64;
    const int w = threadIdx.x >> 6;
    const int o = threadIdx.x & 63;
    const int rp = w >> 1;                  // row slot (0..1)
    const int h = w & 1;                    // CIN-half
    const int k = blockIdx.y;

    float wcol[64];
    const float* __restrict__ Wk =
        W + (size_t)k * CIN * COUT + (size_t)(h * 64) * COUT + o;
#pragma unroll
    for (int i = 0; i < 64; ++i) wcol[i] = Wk[(size_t)i * COUT];

    const int rbase = k * P + blockIdx.x * RPB + rp;

    for (int it = 0; it < RPB / 2; ++it) {
        const int r = rbase + it * 2;       // exact grid: always in-bounds
        const int in = in_idx[r];
        const int orow = out_idx[r];
        const float4* __restrict__ xr4 =
            (const float4*)(x + (size_t)in * CIN + h * 64);
        float a0 = 0.f, a1 = 0.f, a2 = 0.f, a3 = 0.f;
#pragma unroll
        for (int i4 = 0; i4 < 16; ++i4) {
            const float4 xv = xr4[i4];
            a0 = fmaf(xv.x, wcol[4 * i4 + 0], a0);
            a1 = fmaf(xv.y, wcol[4 * i4 + 1], a1);
            a2 = fmaf(xv.z, wcol[4 * i4 + 2], a2);
            a3 = fmaf(xv.w, wcol[4 * i4 + 3], a3);
        }
        atomicAdd(&out[(size_t)orow * COUT + o], (a0 + a1) + (a2 + a3));
    }
}

// ---------------------------------------------------------------------------
// reduce_stats: per-channel sum and sum-of-squares over n_rows rows.
// ---------------------------------------------------------------------------
template <int COUT>
__global__ __launch_bounds__(256) void reduce_stats(
    const float* __restrict__ out, float* __restrict__ stats, int n_rows)
{
    const int RPP = 256 / COUT;
    int c = threadIdx.x % COUT;
    float s = 0.f, ss = 0.f;
    int g = threadIdx.x / COUT;
    for (long long row = (long long)blockIdx.x * RPP + g; row < n_rows;
         row += (long long)gridDim.x * RPP) {
        float v = out[row * COUT + c];
        s += v;
        ss += v * v;
    }
    __shared__ float sh_s[256];
    __shared__ float sh_ss[256];
    sh_s[threadIdx.x] = s;
    sh_ss[threadIdx.x] = ss;
    __syncthreads();
    for (int off = 128; off >= COUT; off >>= 1) {
        if (threadIdx.x < off) {
            sh_s[threadIdx.x] += sh_s[threadIdx.x + off];
            sh_ss[threadIdx.x] += sh_ss[threadIdx.x + off];
        }
        __syncthreads();
    }
    if (threadIdx.x < COUT) {
        atomicAdd(&stats[c], sh_s[c]);
        atomicAdd(&stats[COUT + c], sh_ss[c]);
    }
}

// ---------------------------------------------------------------------------
// bn_skip: y = (v - mean) * rsqrt(var + eps) * gamma + beta + skip, in place.
// ---------------------------------------------------------------------------
template <int COUT>
__global__ __launch_bounds__(256) void bn_skip(
    float* __restrict__ out, const float* __restrict__ skip,
    const float* __restrict__ gamma, const float* __restrict__ beta,
    const float* __restrict__ stats, int n_rows)
{
    const int C4 = COUT / 4;
    long long idx = (long long)blockIdx.x * blockDim.x + threadIdx.x;
    long long total = (long long)n_rows * C4;
    if (idx >= total) return;
    int c4 = (int)(idx % C4);
    float4 v = ((const float4*)out)[idx];
    float4 sk = ((const float4*)skip)[idx];
    float inv_n = 1.f / (float)n_rows;
    float r[4] = {v.x, v.y, v.z, v.w};
    float skv[4] = {sk.x, sk.y, sk.z, sk.w};
#pragma unroll
    for (int j = 0; j < 4; ++j) {
        int c = c4 * 4 + j;
        float mean = stats[c] * inv_n;
        float var = stats[COUT + c] * inv_n - mean * mean;
        float scale = rsqrtf(var + EPS) * gamma[c];
        r[j] = (r[j] - mean) * scale + beta[c] + skv[j];
    }
    float4 res = {r[0], r[1], r[2], r[3]};
    ((float4*)out)[idx] = res;
}

extern "C" void kernel_launch(void* const* d_in, const int* in_sizes, int n_in,
                              void* d_out, int out_size, void* d_ws, size_t ws_size,
                              hipStream_t stream) {
    const float* x3    = (const float*)d_in[0];
    const float* skip3 = (const float*)d_in[1];
    const float* skip2 = (const float*)d_in[2];
    const float* skip1 = (const float*)d_in[3];
    const float* W3    = (const float*)d_in[4];
    const float* W2    = (const float*)d_in[5];
    const float* W1    = (const float*)d_in[6];
    const float* gamma3 = (const float*)d_in[7];
    const float* beta3  = (const float*)d_in[8];
    const float* gamma2 = (const float*)d_in[9];
    const float* beta2  = (const float*)d_in[10];
    const float* gamma1 = (const float*)d_in[11];
    const float* beta1  = (const float*)d_in[12];
    const int* in_idx3  = (const int*)d_in[13];
    const int* out_idx3 = (const int*)d_in[14];
    const int* in_idx2  = (const int*)d_in[15];
    const int* out_idx2 = (const int*)d_in[16];
    const int* in_idx1  = (const int*)d_in[17];
    const int* out_idx1 = (const int*)d_in[18];

    const int N3 = 40000, N2 = 160000, N1 = 640000, N0 = 2560000;
    const int K = 9;

    float* buf3  = (float*)d_ws;                    // N2 * 64
    float* buf2  = buf3 + (size_t)N2 * 64;          // N1 * 32
    float* stats = buf2 + (size_t)N1 * 32;          // 128 floats

    float* outp = (float*)d_out;                    // N0 * 32

    // ---------------- Level 3: x3[N3,128] -> buf3[N2,64] ----------------
    hipMemsetAsync(buf3, 0, (size_t)N2 * 64 * sizeof(float), stream);
    hipMemsetAsync(stats, 0, 128 * sizeof(float), stream);
    {
        const int RPB = 16;                 // 40000/16 = 2500 exact
        dim3 grid(N3 / RPB, K);
        scatter_gemm_l3w<RPB><<<grid, 256, 0, stream>>>(
            x3, W3, in_idx3, out_idx3, buf3, N3);
    }
    reduce_stats<64><<<1024, 256, 0, stream>>>(buf3, stats, N2);
    {
        long long tot = (long long)N2 * (64 / 4);
        bn_skip<64><<<(int)((tot + 255) / 256), 256, 0, stream>>>(
            buf3, skip3, gamma3, beta3, stats, N2);
    }

    // ---------------- Level 2: buf3[N2,64] -> buf2[N1,32] ----------------
    hipMemsetAsync(buf2, 0, (size_t)N1 * 32 * sizeof(float), stream);
    hipMemsetAsync(stats, 0, 128 * sizeof(float), stream);
    {
        const int RPB = 32;                 // 160000/32 = 5000 exact
        dim3 grid(N2 / RPB, K);
        scatter_gemm_h2u<64, RPB><<<grid, 256, 0, stream>>>(
            buf3, W2, in_idx2, out_idx2, buf2, N2);
    }
    reduce_stats<32><<<2048, 256, 0, stream>>>(buf2, stats, N1);
    {
        long long tot = (long long)N1 * (32 / 4);
        bn_skip<32><<<(int)((tot + 255) / 256), 256, 0, stream>>>(
            buf2, skip2, gamma2, beta2, stats, N1);
    }

    // ---------------- Level 1: buf2[N1,32] -> d_out[N0,32] ----------------
    hipMemsetAsync(outp, 0, (size_t)N0 * 32 * sizeof(float), stream);
    hipMemsetAsync(stats, 0, 128 * sizeof(float), stream);
    {
        const int RPB = 64;                 // 640000/64 = 10000 exact
        dim3 grid(N1 / RPB, K);
        scatter_gemm_wreg2<32, 32, RPB><<<grid, 256, 0, stream>>>(
            buf2, W1, in_idx1, out_idx1, outp, N1);
    }
    reduce_stats<32><<<4096, 256, 0, stream>>>(outp, stats, N0);
    {
        long long tot = (long long)N0 * (32 / 4);
        bn_skip<32><<<(int)((tot + 255) / 256), 256, 0, stream>>>(
            outp, skip1, gamma1, beta1, stats, N0);
    }
}